// Round 3
// baseline (144.269 us; speedup 1.0000x reference)
//
#include <hip/hip_runtime.h>
#include <hip/hip_bf16.h>
#include <stdint.h>

#define NPAIRS 500000
#define NNODES 100000
#define DIM    128
#define D2     256
#define BM     128
#define TPB    4                                    // tiles per block
#define NTILE  ((NPAIRS + BM - 1) / BM)             // 3907
#define NBLK   ((NTILE + TPB - 1) / TPB)            // 977

typedef __bf16 bf16;
typedef __bf16 bf16x8 __attribute__((ext_vector_type(8)));
typedef float  f32x4  __attribute__((ext_vector_type(4)));

#define FENCE() asm volatile("" ::: "memory")

// ---- prep: x (fp32, 100000x128) -> bf16 rows of 256B ----
__global__ void convert_x(const float* __restrict__ x, bf16* __restrict__ xb) {
    long t = (long)blockIdx.x * 256 + threadIdx.x;   // 1,600,000 threads exactly
    const float4* src = (const float4*)(x + t * 8);
    float4 a = src[0], b = src[1];
    bf16x8 v;
    v[0] = (bf16)a.x; v[1] = (bf16)a.y; v[2] = (bf16)a.z; v[3] = (bf16)a.w;
    v[4] = (bf16)b.x; v[5] = (bf16)b.y; v[6] = (bf16)b.z; v[7] = (bf16)b.w;
    *(bf16x8*)(xb + t * 8) = v;
}

// ---- prep: W1 (256x256 fp32) -> bf16 MFMA B-fragments in per-lane order ----
// w1f[((cg*8 + kk)*64 + lane)*8 + j] = W1[kk*32 + (lane>>4)*8 + j][cg*16 + (lane&15)]
__global__ void pack_w1(const float* __restrict__ W1, bf16* __restrict__ w1f) {
    int t = blockIdx.x * 256 + threadIdx.x;   // 0..8191
    int lane = t & 63;
    int kkcg = t >> 6;
    int kk = kkcg & 7;
    int cg = kkcg >> 3;
    int l15 = lane & 15, lg = lane >> 4;
    bf16x8 v;
#pragma unroll
    for (int j = 0; j < 8; ++j) {
        int k = kk * 32 + lg * 8 + j;
        int n = cg * 16 + l15;
        v[j] = (bf16)W1[k * D2 + n];
    }
    *(bf16x8*)((char*)w1f + ((long)t << 4)) = v;
}

__device__ __forceinline__ void gld16(void* lds, const void* g) {
    __builtin_amdgcn_global_load_lds(
        (const __attribute__((address_space(1))) uint32_t*)g,
        (__attribute__((address_space(3))) uint32_t*)lds, 16, 0, 0);
}

// 8 waves (2 row-groups x 4 col-groups), BM=128 pairs/tile, TPB tiles/block,
// double-buffered async A-stage, W1 fragments resident in registers.
template<bool PRE>
__launch_bounds__(512, 2)
__global__ void gnn_main(const float* __restrict__ x,
                         const bf16*  __restrict__ xb,
                         const int*   __restrict__ junc,
                         const bf16*  __restrict__ w1f,
                         const float* __restrict__ b1,
                         const float* __restrict__ w2p,
                         const float* __restrict__ b2,
                         float*       __restrict__ out) {
    __shared__ __align__(1024) char atile[2][BM * 512];  // 2 x 64 KB, XOR-swizzled
    __shared__ float outp[TPB][4][BM];                    // 8 KB per-tile/per-wc partials

    int tid  = threadIdx.x;
    int wave = tid >> 6, lane = tid & 63;
    int l15 = lane & 15, lg = lane >> 4;
    int wr = wave >> 2, wc = wave & 3;
    long tile0 = (long)blockIdx.x * TPB;

    // ---- block-resident W1 fragments: 32 x bf16x8 = 128 VGPR ----
    bf16x8 breg[4][8];
#pragma unroll
    for (int n = 0; n < 4; ++n)
#pragma unroll
        for (int kk = 0; kk < 8; ++kk) {
            int cg = wc * 4 + n;
            breg[n][kk] = *(const bf16x8*)((const char*)w1f + (((cg * 8 + kk) * 64 + lane) << 4));
        }
    float bb[4], ww[4];
#pragma unroll
    for (int n = 0; n < 4; ++n) {
        int col = wc * 64 + n * 16 + l15;
        bb[n] = b1[col];
        ww[n] = w2p[col];
    }

    // ---- stage one tile's A into buf b (async for PRE, reg-staged otherwise) ----
    auto stage = [&](char* buf, long ti) {
        long base_p = ti * BM;
        if (PRE) {
            int idx8[8];
#pragma unroll
            for (int i = 0; i < 8; ++i) {
                int lds_off = wave * 8192 + i * 1024 + lane * 16;
                int r    = lds_off >> 9;
                int sbir = (lds_off & 511) ^ ((r & 7) << 4);  // inverse swizzle
                int side = sbir >> 8;
                long p   = base_p + r;
                idx8[i]  = (p < NPAIRS) ? junc[p * 2 + side] : 0;
            }
#pragma unroll
            for (int i = 0; i < 8; ++i) {
                int lds_off = wave * 8192 + i * 1024 + lane * 16;
                int r    = lds_off >> 9;
                int sbir = (lds_off & 511) ^ ((r & 7) << 4);
                gld16(buf + wave * 8192 + i * 1024,
                      (const char*)xb + ((long)idx8[i] << 8) + (sbir & 255));
            }
        } else {
#pragma unroll
            for (int it = 0; it < 8; ++it) {
                int task  = it * 512 + tid;       // 0..4095
                int nr    = task >> 4;
                int chunk = task & 15;
                int r     = nr >> 1;
                int side  = nr & 1;
                long p    = base_p + r;
                int idx   = (p < NPAIRS) ? junc[p * 2 + side] : 0;
                const float4* src = (const float4*)(x + (long)idx * DIM + chunk * 8);
                float4 a = src[0], b = src[1];
                bf16x8 v;
                v[0] = (bf16)a.x; v[1] = (bf16)a.y; v[2] = (bf16)a.z; v[3] = (bf16)a.w;
                v[4] = (bf16)b.x; v[5] = (bf16)b.y; v[6] = (bf16)b.z; v[7] = (bf16)b.w;
                int bir = side * 256 + chunk * 16;
                *(bf16x8*)(buf + r * 512 + (bir ^ ((r & 7) << 4))) = v;
            }
        }
    };

    // ---- prologue: stage tile 0, full drain, raw barrier ----
    stage(atile[0], tile0);
    FENCE();
    asm volatile("s_waitcnt vmcnt(0) lgkmcnt(0)" ::: "memory");
    __builtin_amdgcn_s_barrier();
    FENCE();

#pragma unroll 1
    for (int t = 0; t < TPB; ++t) {
        // issue next tile's stage first: loads fly under this tile's compute
        if (t + 1 < TPB) stage(atile[(t + 1) & 1], tile0 + t + 1);
        FENCE();

        const char* buf = atile[t & 1];
        f32x4 acc[4][4];
#pragma unroll
        for (int m = 0; m < 4; ++m)
#pragma unroll
            for (int n = 0; n < 4; ++n)
                acc[m][n] = (f32x4){0.f, 0.f, 0.f, 0.f};

#pragma unroll
        for (int kk = 0; kk < 8; ++kk) {
            bf16x8 af[4];
            int kbyte = kk * 64 + lg * 16;
#pragma unroll
            for (int m = 0; m < 4; ++m) {
                int r = wr * 64 + m * 16 + l15;
                af[m] = *(const bf16x8*)(buf + r * 512 + (kbyte ^ ((r & 7) << 4)));
            }
#pragma unroll
            for (int m = 0; m < 4; ++m)
#pragma unroll
                for (int n = 0; n < 4; ++n)
                    acc[m][n] = __builtin_amdgcn_mfma_f32_16x16x32_bf16(af[m], breg[n][kk], acc[m][n], 0, 0, 0);
        }

        // epilogue: fp32 bias+relu+dot(W2), 16-lane reduce, park partials in LDS
#pragma unroll
        for (int m = 0; m < 4; ++m) {
            float s[4] = {0.f, 0.f, 0.f, 0.f};
#pragma unroll
            for (int n = 0; n < 4; ++n) {
#pragma unroll
                for (int r = 0; r < 4; ++r) {
                    float h = acc[m][n][r] + bb[n];
                    h = fmaxf(h, 0.f);
                    s[r] = fmaf(h, ww[n], s[r]);
                }
            }
#pragma unroll
            for (int r = 0; r < 4; ++r) {
                float v = s[r];
                v += __shfl_xor(v, 1);
                v += __shfl_xor(v, 2);
                v += __shfl_xor(v, 4);
                v += __shfl_xor(v, 8);
                if (l15 == 0) outp[t][wc][wr * 64 + m * 16 + lg * 4 + r] = v;
            }
        }

        // tile boundary: drain (stage t+1 landed long ago), raw barrier
        FENCE();
        asm volatile("s_waitcnt vmcnt(0) lgkmcnt(0)" ::: "memory");
        __builtin_amdgcn_s_barrier();
        FENCE();
    }

    __syncthreads();   // full fence once per block before cross-wave outp reads

    {
        int t2 = tid >> 7, row = tid & 127;
        long p = tile0 * BM + t2 * BM + row;
        if (p < NPAIRS) {
            float v = b2[0] + outp[t2][0][row] + outp[t2][1][row]
                            + outp[t2][2][row] + outp[t2][3][row];
            out[p] = v;
        }
    }
}

extern "C" void kernel_launch(void* const* d_in, const int* in_sizes, int n_in,
                              void* d_out, int out_size, void* d_ws, size_t ws_size,
                              hipStream_t stream) {
    const float* x    = (const float*)d_in[0];
    const int*   junc = (const int*)  d_in[1];
    const float* W1   = (const float*)d_in[2];
    const float* b1   = (const float*)d_in[3];
    const float* W2   = (const float*)d_in[4];
    const float* b2   = (const float*)d_in[5];
    float* out = (float*)d_out;

    const size_t XB_BYTES = (size_t)NNODES * DIM * 2;   // 25,600,000
    const size_t NEED     = XB_BYTES + 131072;

    if (ws_size >= NEED) {
        bf16* xb  = (bf16*)d_ws;
        bf16* w1f = (bf16*)((char*)d_ws + XB_BYTES);
        hipLaunchKernelGGL(convert_x, dim3(6250), dim3(256), 0, stream, x, xb);
        hipLaunchKernelGGL(pack_w1, dim3(32), dim3(256), 0, stream, W1, w1f);
        hipLaunchKernelGGL((gnn_main<true>), dim3(NBLK), dim3(512), 0, stream,
                           x, xb, junc, w1f, b1, W2, b2, out);
    } else {
        bf16* w1f = (bf16*)d_ws;
        hipLaunchKernelGGL(pack_w1, dim3(32), dim3(256), 0, stream, W1, w1f);
        hipLaunchKernelGGL((gnn_main<false>), dim3(NBLK), dim3(512), 0, stream,
                           x, (const bf16*)nullptr, junc, w1f, b1, W2, b2, out);
    }
}

// Round 4
// 129.892 us; speedup vs baseline: 1.1107x; 1.1107x over previous
//
#include <hip/hip_runtime.h>
#include <hip/hip_bf16.h>
#include <stdint.h>

#define NPAIRS 500000
#define NNODES 100000
#define DIM    128
#define D2     256
#define BM     128
#define TPB    4                                    // tiles per block
#define NTILE  ((NPAIRS + BM - 1) / BM)             // 3907
#define NBLK   ((NTILE + TPB - 1) / TPB)            // 977

typedef __bf16 bf16;
typedef __bf16 bf16x8 __attribute__((ext_vector_type(8)));
typedef float  f32x4  __attribute__((ext_vector_type(4)));

#define FENCE() asm volatile("" ::: "memory")

// ---- prep: x (fp32, 100000x128) -> bf16 rows of 256B ----
__global__ void convert_x(const float* __restrict__ x, bf16* __restrict__ xb) {
    long t = (long)blockIdx.x * 256 + threadIdx.x;   // 1,600,000 threads exactly
    const float4* src = (const float4*)(x + t * 8);
    float4 a = src[0], b = src[1];
    bf16x8 v;
    v[0] = (bf16)a.x; v[1] = (bf16)a.y; v[2] = (bf16)a.z; v[3] = (bf16)a.w;
    v[4] = (bf16)b.x; v[5] = (bf16)b.y; v[6] = (bf16)b.z; v[7] = (bf16)b.w;
    *(bf16x8*)(xb + t * 8) = v;
}

// ---- prep: W1 (256x256 fp32) -> bf16 fragments in per-lane order ----
// w1f[((cg*8 + kk)*64 + lane)*8 + j] = W1[kk*32 + (lane>>4)*8 + j][cg*16 + (lane&15)]
// Used as the MFMA *A* operand (W1^T tile: row = h-col = lane&15, k = lg*8+j).
__global__ void pack_w1(const float* __restrict__ W1, bf16* __restrict__ w1f) {
    int t = blockIdx.x * 256 + threadIdx.x;   // 0..8191
    int lane = t & 63;
    int kkcg = t >> 6;
    int kk = kkcg & 7;
    int cg = kkcg >> 3;
    int l15 = lane & 15, lg = lane >> 4;
    bf16x8 v;
#pragma unroll
    for (int j = 0; j < 8; ++j) {
        int k = kk * 32 + lg * 8 + j;
        int n = cg * 16 + l15;
        v[j] = (bf16)W1[k * D2 + n];
    }
    *(bf16x8*)((char*)w1f + ((long)t << 4)) = v;
}

__device__ __forceinline__ void gld16(void* lds, const void* g) {
    __builtin_amdgcn_global_load_lds(
        (const __attribute__((address_space(1))) uint32_t*)g,
        (__attribute__((address_space(3))) uint32_t*)lds, 16, 0, 0);
}

// 8 waves: wr = wave>>2 splits 128 pairs into 2x64; wc = wave&3 splits 256
// h-cols into 4x64. Computes H^T blocks: mfma(A = W1^T frag, B = X^T frag).
// D: col(lane&15) = pair, row(lg*4+r) = h-col  ->  W2-dot is in-register.
template<bool PRE>
__launch_bounds__(512, 2)
__global__ void gnn_main(const float* __restrict__ x,
                         const bf16*  __restrict__ xb,
                         const int*   __restrict__ junc,
                         const bf16*  __restrict__ w1f,
                         const float* __restrict__ b1,
                         const float* __restrict__ w2p,
                         const float* __restrict__ b2,
                         float*       __restrict__ out) {
    __shared__ __align__(1024) char atile[2][BM * 512];  // 2 x 64 KB, XOR-swizzled
    __shared__ float outp[TPB][4][BM];                    // 8 KB partials [t][wc][pair]

    int tid  = threadIdx.x;
    int wave = tid >> 6, lane = tid & 63;
    int l15 = lane & 15, lg = lane >> 4;
    int wr = wave >> 2, wc = wave & 3;
    long tile0 = (long)blockIdx.x * TPB;

    // half-resident W1^T frags: m=0,1 in regs (64 VGPR); m=2,3 streamed per kk
    bf16x8 breg[2][8];
#pragma unroll
    for (int m = 0; m < 2; ++m)
#pragma unroll
        for (int kk = 0; kk < 8; ++kk)
            breg[m][kk] = *(const bf16x8*)((const char*)w1f +
                              ((((wc * 4 + m) * 8 + kk) * 64 + lane) << 4));

    // per-lane bias + W2 weights for this lane's 16 h-cols
    float bb[4][4], ww[4][4];
#pragma unroll
    for (int m = 0; m < 4; ++m)
#pragma unroll
        for (int r = 0; r < 4; ++r) {
            int hc = wc * 64 + m * 16 + lg * 4 + r;
            bb[m][r] = b1[hc];
            ww[m][r] = w2p[hc];
        }

    auto stage = [&](char* buf, long ti) {
        long base_p = ti * BM;
        if (PRE) {
            int idx8[8];
#pragma unroll
            for (int i = 0; i < 8; ++i) {
                int lds_off = wave * 8192 + i * 1024 + lane * 16;
                int r    = lds_off >> 9;
                int sbir = (lds_off & 511) ^ ((r & 7) << 4);  // inverse swizzle
                int side = sbir >> 8;
                long p   = base_p + r;
                idx8[i]  = (p < NPAIRS) ? junc[p * 2 + side] : 0;
            }
#pragma unroll
            for (int i = 0; i < 8; ++i) {
                int lds_off = wave * 8192 + i * 1024 + lane * 16;
                int r    = lds_off >> 9;
                int sbir = (lds_off & 511) ^ ((r & 7) << 4);
                gld16(buf + wave * 8192 + i * 1024,
                      (const char*)xb + ((long)idx8[i] << 8) + (sbir & 255));
            }
        } else {
#pragma unroll
            for (int it = 0; it < 8; ++it) {
                int task  = it * 512 + tid;       // 0..4095
                int nr    = task >> 4;
                int chunk = task & 15;
                int r     = nr >> 1;
                int side  = nr & 1;
                long p    = base_p + r;
                int idx   = (p < NPAIRS) ? junc[p * 2 + side] : 0;
                const float4* src = (const float4*)(x + (long)idx * DIM + chunk * 8);
                float4 a = src[0], b = src[1];
                bf16x8 v;
                v[0] = (bf16)a.x; v[1] = (bf16)a.y; v[2] = (bf16)a.z; v[3] = (bf16)a.w;
                v[4] = (bf16)b.x; v[5] = (bf16)b.y; v[6] = (bf16)b.z; v[7] = (bf16)b.w;
                int bir = side * 256 + chunk * 16;
                *(bf16x8*)(buf + r * 512 + (bir ^ ((r & 7) << 4))) = v;
            }
        }
    };

    // prologue: stage tile 0, drain, barrier
    stage(atile[0], tile0);
    FENCE();
    asm volatile("s_waitcnt vmcnt(0) lgkmcnt(0)" ::: "memory");
    __builtin_amdgcn_s_barrier();
    FENCE();

#pragma unroll 1
    for (int t = 0; t < TPB; ++t) {
        if (t + 1 < TPB) stage(atile[(t + 1) & 1], tile0 + t + 1);  // issue early
        FENCE();

        const char* buf = atile[t & 1];
        f32x4 acc[4][4];
#pragma unroll
        for (int m = 0; m < 4; ++m)
#pragma unroll
            for (int n = 0; n < 4; ++n)
                acc[m][n] = (f32x4){0.f, 0.f, 0.f, 0.f};

#pragma unroll
        for (int kk = 0; kk < 8; ++kk) {
            bf16x8 xf[4];
            int kbyte = kk * 64 + lg * 16;
#pragma unroll
            for (int n = 0; n < 4; ++n) {
                int r = wr * 64 + n * 16 + l15;
                xf[n] = *(const bf16x8*)(buf + r * 512 + (kbyte ^ ((r & 7) << 4)));
            }
            bf16x8 ws0 = *(const bf16x8*)((const char*)w1f +
                             ((((wc * 4 + 2) * 8 + kk) * 64 + lane) << 4));
            bf16x8 ws1 = *(const bf16x8*)((const char*)w1f +
                             ((((wc * 4 + 3) * 8 + kk) * 64 + lane) << 4));
#pragma unroll
            for (int n = 0; n < 4; ++n) {
                acc[0][n] = __builtin_amdgcn_mfma_f32_16x16x32_bf16(breg[0][kk], xf[n], acc[0][n], 0, 0, 0);
                acc[1][n] = __builtin_amdgcn_mfma_f32_16x16x32_bf16(breg[1][kk], xf[n], acc[1][n], 0, 0, 0);
                acc[2][n] = __builtin_amdgcn_mfma_f32_16x16x32_bf16(ws0,        xf[n], acc[2][n], 0, 0, 0);
                acc[3][n] = __builtin_amdgcn_mfma_f32_16x16x32_bf16(ws1,        xf[n], acc[3][n], 0, 0, 0);
            }
        }

        // epilogue: bias+relu+W2 dot in-register over this wave's 64 h-cols,
        // then 2 shfl to fold the lg axis; lane lg==0 parks the pair partial.
#pragma unroll
        for (int n = 0; n < 4; ++n) {
            float s = 0.f;
#pragma unroll
            for (int m = 0; m < 4; ++m)
#pragma unroll
                for (int r = 0; r < 4; ++r)
                    s = fmaf(fmaxf(acc[m][n][r] + bb[m][r], 0.f), ww[m][r], s);
            s += __shfl_xor(s, 16);
            s += __shfl_xor(s, 32);
            if (lg == 0) outp[t][wc][wr * 64 + n * 16 + l15] = s;
        }

        FENCE();
        asm volatile("s_waitcnt vmcnt(0) lgkmcnt(0)" ::: "memory");
        __builtin_amdgcn_s_barrier();
        FENCE();
    }

    __syncthreads();

    {
        int t2 = tid >> 7, row = tid & 127;
        long p = tile0 * BM + t2 * BM + row;
        if (p < NPAIRS) {
            out[p] = b2[0] + outp[t2][0][row] + outp[t2][1][row]
                           + outp[t2][2][row] + outp[t2][3][row];
        }
    }
}

extern "C" void kernel_launch(void* const* d_in, const int* in_sizes, int n_in,
                              void* d_out, int out_size, void* d_ws, size_t ws_size,
                              hipStream_t stream) {
    const float* x    = (const float*)d_in[0];
    const int*   junc = (const int*)  d_in[1];
    const float* W1   = (const float*)d_in[2];
    const float* b1   = (const float*)d_in[3];
    const float* W2   = (const float*)d_in[4];
    const float* b2   = (const float*)d_in[5];
    float* out = (float*)d_out;

    const size_t XB_BYTES = (size_t)NNODES * DIM * 2;   // 25,600,000
    const size_t NEED     = XB_BYTES + 131072;

    if (ws_size >= NEED) {
        bf16* xb  = (bf16*)d_ws;
        bf16* w1f = (bf16*)((char*)d_ws + XB_BYTES);
        hipLaunchKernelGGL(convert_x, dim3(6250), dim3(256), 0, stream, x, xb);
        hipLaunchKernelGGL(pack_w1, dim3(32), dim3(256), 0, stream, W1, w1f);
        hipLaunchKernelGGL((gnn_main<true>), dim3(NBLK), dim3(512), 0, stream,
                           x, xb, junc, w1f, b1, W2, b2, out);
    } else {
        bf16* w1f = (bf16*)d_ws;
        hipLaunchKernelGGL(pack_w1, dim3(32), dim3(256), 0, stream, W1, w1f);
        hipLaunchKernelGGL((gnn_main<false>), dim3(NBLK), dim3(512), 0, stream,
                           x, (const bf16*)nullptr, junc, w1f, b1, W2, b2, out);
    }
}